// Round 3
// baseline (701.646 us; speedup 1.0000x reference)
//
#include <hip/hip_runtime.h>

#define BI 4
#define TT 2048
#define EE 1024
#define HH 16
#define DD 64
// M = BI*TT = 8192

typedef short bf16x8 __attribute__((ext_vector_type(8)));
typedef float f32x4 __attribute__((ext_vector_type(4)));
typedef unsigned short u16;

__device__ __forceinline__ float bf2f(u16 v) {
    unsigned int u = ((unsigned int)v) << 16;
    return __builtin_bit_cast(float, u);
}
__device__ __forceinline__ u16 f2bf(float f) {
    unsigned int u = __builtin_bit_cast(unsigned int, f);
    unsigned int r = (u + 0x7fffu + ((u >> 16) & 1u)) >> 16;
    return (u16)r;
}

// ---------------- Kernel 1: QKV projection ----------------
// out[b][h][t][d] = sum_e data[b][t][e] * W[h][e][d]   (q scaled by 0.125)
// data: f32 [B,T,E]; W: f32 [H,E,D]; out: bf16 workspace
__global__ __launch_bounds__(256) void qkv_gemm(
    const float* __restrict__ data, const float* __restrict__ Wq,
    const float* __restrict__ Wk, const float* __restrict__ Wv,
    u16* __restrict__ qws, u16* __restrict__ kws, u16* __restrict__ vws)
{
    const int z = blockIdx.z;
    const float* W = (z == 0) ? Wq : ((z == 1) ? Wk : Wv);
    u16* out = (z == 0) ? qws : ((z == 1) ? kws : vws);
    const int h  = blockIdx.y;
    const int m0 = blockIdx.x * 128;
    const int b  = m0 / TT;
    const int t0 = m0 % TT;

    __shared__ u16 As[128][72];   // A tile [row][e] (bf16)
    __shared__ u16 Bs[64][72];    // B^T tile [d][e] (bf16)

    const int tid = threadIdx.x;
    const int l  = tid & 63;
    const int w  = tid >> 6;
    const int wr = w >> 1;    // 0..1 (64-row half)
    const int wc = w & 1;     // 0..1 (32-col half)
    const int lr = l & 15;
    const int lk = l >> 4;

    f32x4 acc[4][2];
    for (int i = 0; i < 4; ++i)
        for (int j = 0; j < 2; ++j)
            acc[i][j] = (f32x4){0.f, 0.f, 0.f, 0.f};

    for (int e0 = 0; e0 < EE; e0 += 64) {
        // stage A: 128x64 f32 -> bf16 (coalesced float4 loads)
        const float* dsrc = data + (size_t)m0 * EE + e0;
        for (int it = 0; it < 8; ++it) {
            int v = tid + it * 256;           // 0..2047
            int row = v >> 4, c4 = v & 15;
            float4 x = *reinterpret_cast<const float4*>(dsrc + (size_t)row * EE + c4 * 4);
            ushort4 p;
            p.x = f2bf(x.x); p.y = f2bf(x.y); p.z = f2bf(x.z); p.w = f2bf(x.w);
            *reinterpret_cast<ushort4*>(&As[row][c4 * 4]) = p;
        }
        // stage B^T: W[h][e0+e][d] f32 -> Bs[d][e] bf16
        const float* wsrc = W + ((size_t)h * EE + e0) * DD;
        for (int it = 0; it < 4; ++it) {
            int v = tid + it * 256;           // 0..1023
            int e = v >> 4, d4 = v & 15;
            float4 x = *reinterpret_cast<const float4*>(wsrc + (size_t)e * DD + d4 * 4);
            Bs[d4 * 4 + 0][e] = f2bf(x.x);
            Bs[d4 * 4 + 1][e] = f2bf(x.y);
            Bs[d4 * 4 + 2][e] = f2bf(x.z);
            Bs[d4 * 4 + 3][e] = f2bf(x.w);
        }
        __syncthreads();
        for (int kk = 0; kk < 64; kk += 32) {
            bf16x8 a[4], bb[2];
            for (int fr = 0; fr < 4; ++fr)
                a[fr] = *reinterpret_cast<const bf16x8*>(&As[wr * 64 + fr * 16 + lr][kk + lk * 8]);
            for (int fc = 0; fc < 2; ++fc)
                bb[fc] = *reinterpret_cast<const bf16x8*>(&Bs[wc * 32 + fc * 16 + lr][kk + lk * 8]);
            for (int fr = 0; fr < 4; ++fr)
                for (int fc = 0; fc < 2; ++fc)
                    acc[fr][fc] = __builtin_amdgcn_mfma_f32_16x16x32_bf16(a[fr], bb[fc], acc[fr][fc], 0, 0, 0);
        }
        __syncthreads();
    }

    const float scale = (z == 0) ? 0.125f : 1.0f;
    for (int fr = 0; fr < 4; ++fr) {
        int row = wr * 64 + fr * 16 + lk * 4;
        for (int fc = 0; fc < 2; ++fc) {
            int col = wc * 32 + fc * 16 + lr;
            size_t base = (((size_t)b * HH + h) * TT + (size_t)(t0 + row)) * DD + col;
            for (int rr = 0; rr < 4; ++rr)
                out[base + (size_t)rr * DD] = f2bf(acc[fr][fc][rr] * scale);
        }
    }
}

// ---------------- Kernel 2: causal flash attention ----------------
// aout[b][t][h*64+d]  (all bf16, workspace-to-workspace)
__global__ __launch_bounds__(256) void attn(
    const u16* __restrict__ qws, const u16* __restrict__ kws,
    const u16* __restrict__ vws, u16* __restrict__ aout)
{
    const int qt = blockIdx.x;        // 0..31 (64-row q tile)
    const int bh = blockIdx.y;        // 0..63
    const int b = bh >> 4, h = bh & 15;
    const int q0 = qt * 64;

    __shared__ u16 Ks[32][72];        // K tile [s][d]
    __shared__ u16 Vt[64][48];        // V^T tile [d][s]
    __shared__ u16 Pb[4][16][48];     // per-wave P round-trip [q][s]

    const int tid = threadIdx.x;
    const int l = tid & 63;
    const int w = tid >> 6;
    const int lr = l & 15, lk = l >> 4;

    const size_t kvbase = ((size_t)bh) * TT * DD;
    const int qb = q0 + w * 16;       // this wave's 16 q-rows

    bf16x8 qf[2];
    for (int kf = 0; kf < 2; ++kf)
        qf[kf] = *reinterpret_cast<const bf16x8*>(qws + kvbase + (size_t)(qb + lr) * DD + kf * 32 + lk * 8);

    f32x4 oacc[4];
    for (int i = 0; i < 4; ++i) oacc[i] = (f32x4){0.f, 0.f, 0.f, 0.f};
    float mrow[4], lsum[4];
    for (int r = 0; r < 4; ++r) { mrow[r] = -INFINITY; lsum[r] = 0.f; }

    const int ntiles = 2 * qt + 2;
    for (int j = 0; j < ntiles; ++j) {
        const int s0 = j * 32;
        // stage K,V tile (each thread one 16B vec)
        {
            int row = tid >> 3, d8 = tid & 7;
            uint4 kx = reinterpret_cast<const uint4*>(kws + kvbase + (size_t)(s0 + row) * DD)[d8];
            *reinterpret_cast<uint4*>(&Ks[row][d8 * 8]) = kx;
            uint4 vx = reinterpret_cast<const uint4*>(vws + kvbase + (size_t)(s0 + row) * DD)[d8];
            const u16* vs = reinterpret_cast<const u16*>(&vx);
            for (int ii = 0; ii < 8; ++ii) Vt[d8 * 8 + ii][row] = vs[ii];
        }
        __syncthreads();
        if (s0 <= qb + 15) {          // not fully masked for this wave
            f32x4 sc[2];
            for (int fc = 0; fc < 2; ++fc) {
                sc[fc] = (f32x4){0.f, 0.f, 0.f, 0.f};
                for (int kk = 0; kk < 2; ++kk) {
                    bf16x8 kfrag = *reinterpret_cast<const bf16x8*>(&Ks[fc * 16 + lr][kk * 32 + lk * 8]);
                    sc[fc] = __builtin_amdgcn_mfma_f32_16x16x32_bf16(qf[kk], kfrag, sc[fc], 0, 0, 0);
                }
            }
            // causal mask (scale already folded into q)
            float pm[2][4];
            for (int fc = 0; fc < 2; ++fc) {
                int scol = s0 + fc * 16 + lr;
                for (int r = 0; r < 4; ++r) {
                    int qrow = qb + lk * 4 + r;
                    float v = sc[fc][r];
                    pm[fc][r] = (scol > qrow) ? -INFINITY : v;
                }
            }
            // row max over 32 s (within 16-lane group)
            float mx[4];
            for (int r = 0; r < 4; ++r) mx[r] = fmaxf(pm[0][r], pm[1][r]);
            for (int off = 1; off < 16; off <<= 1)
                for (int r = 0; r < 4; ++r) mx[r] = fmaxf(mx[r], __shfl_xor(mx[r], off, 64));
            float mnew[4], alpha[4];
            for (int r = 0; r < 4; ++r) {
                mnew[r] = fmaxf(mrow[r], mx[r]);
                alpha[r] = exp2f((mrow[r] - mnew[r]) * 1.44269504f);
            }
            float p[2][4], rsum[4];
            for (int r = 0; r < 4; ++r) {
                p[0][r] = exp2f((pm[0][r] - mnew[r]) * 1.44269504f);
                p[1][r] = exp2f((pm[1][r] - mnew[r]) * 1.44269504f);
                rsum[r] = p[0][r] + p[1][r];
            }
            for (int off = 1; off < 16; off <<= 1)
                for (int r = 0; r < 4; ++r) rsum[r] += __shfl_xor(rsum[r], off, 64);
            for (int r = 0; r < 4; ++r) {
                lsum[r] = lsum[r] * alpha[r] + rsum[r];
                mrow[r] = mnew[r];
            }
            for (int fc = 0; fc < 4; ++fc)
                for (int r = 0; r < 4; ++r)
                    oacc[fc][r] *= alpha[r];
            // P (D-layout) -> LDS -> A-fragment layout
            for (int fc = 0; fc < 2; ++fc)
                for (int r = 0; r < 4; ++r)
                    Pb[w][lk * 4 + r][fc * 16 + lr] = f2bf(p[fc][r]);
            bf16x8 pf = *reinterpret_cast<const bf16x8*>(&Pb[w][lr][lk * 8]);
            for (int fc = 0; fc < 4; ++fc) {
                bf16x8 vf = *reinterpret_cast<const bf16x8*>(&Vt[fc * 16 + lr][lk * 8]);
                oacc[fc] = __builtin_amdgcn_mfma_f32_16x16x32_bf16(pf, vf, oacc[fc], 0, 0, 0);
            }
        }
        __syncthreads();
    }
    // epilogue: concat-head layout [b][t][h*64+d]
    for (int fc = 0; fc < 4; ++fc) {
        int dcol = fc * 16 + lr;
        for (int r = 0; r < 4; ++r) {
            int qrow = qb + lk * 4 + r;
            float v = oacc[fc][r] / lsum[r];
            aout[((size_t)b * TT + qrow) * EE + (size_t)h * DD + dcol] = f2bf(v);
        }
    }
}

// ---------------- Kernel 3: output projection + bias ----------------
// A: bf16 workspace [M,E]; Wp: f32 [E,E]; bp: f32 [E]; out: f32 [M,E]
__global__ __launch_bounds__(256) void proj_gemm(
    const u16* __restrict__ A, const float* __restrict__ Wp,
    const float* __restrict__ bp, float* __restrict__ out)
{
    const int m0 = blockIdx.x * 128;
    const int n0 = blockIdx.y * 64;

    __shared__ u16 As[128][72];
    __shared__ u16 Bs[64][72];    // Wp^T tile [n][e]

    const int tid = threadIdx.x;
    const int l  = tid & 63;
    const int w  = tid >> 6;
    const int wr = w >> 1;
    const int wc = w & 1;
    const int lr = l & 15;
    const int lk = l >> 4;

    f32x4 acc[4][2];
    for (int i = 0; i < 4; ++i)
        for (int j = 0; j < 2; ++j)
            acc[i][j] = (f32x4){0.f, 0.f, 0.f, 0.f};

    for (int e0 = 0; e0 < EE; e0 += 64) {
        // stage A (bf16 workspace, uint4 = 8 elems)
        const uint4* asrc = reinterpret_cast<const uint4*>(A);
        for (int it = 0; it < 4; ++it) {
            int v = tid + it * 256;
            int row = v >> 3, c8 = v & 7;
            uint4 x = asrc[(((size_t)(m0 + row)) * EE + e0) / 8 + c8];
            *reinterpret_cast<uint4*>(&As[row][c8 * 8]) = x;
        }
        // stage B^T: Wp[e0+e][n0+n] f32 -> Bs[n][e] bf16
        const float* wsrc = Wp + (size_t)e0 * EE + n0;
        for (int it = 0; it < 4; ++it) {
            int v = tid + it * 256;           // 0..1023
            int e = v >> 4, n4 = v & 15;
            float4 x = *reinterpret_cast<const float4*>(wsrc + (size_t)e * EE + n4 * 4);
            Bs[n4 * 4 + 0][e] = f2bf(x.x);
            Bs[n4 * 4 + 1][e] = f2bf(x.y);
            Bs[n4 * 4 + 2][e] = f2bf(x.z);
            Bs[n4 * 4 + 3][e] = f2bf(x.w);
        }
        __syncthreads();
        for (int kk = 0; kk < 64; kk += 32) {
            bf16x8 a[4], bb[2];
            for (int fr = 0; fr < 4; ++fr)
                a[fr] = *reinterpret_cast<const bf16x8*>(&As[wr * 64 + fr * 16 + lr][kk + lk * 8]);
            for (int fc = 0; fc < 2; ++fc)
                bb[fc] = *reinterpret_cast<const bf16x8*>(&Bs[wc * 32 + fc * 16 + lr][kk + lk * 8]);
            for (int fr = 0; fr < 4; ++fr)
                for (int fc = 0; fc < 2; ++fc)
                    acc[fr][fc] = __builtin_amdgcn_mfma_f32_16x16x32_bf16(a[fr], bb[fc], acc[fr][fc], 0, 0, 0);
        }
        __syncthreads();
    }

    for (int fr = 0; fr < 4; ++fr) {
        int row = wr * 64 + fr * 16 + lk * 4;
        for (int fc = 0; fc < 2; ++fc) {
            int col = n0 + wc * 32 + fc * 16 + lr;
            float bias = bp[col];
            for (int rr = 0; rr < 4; ++rr)
                out[((size_t)(m0 + row + rr)) * EE + col] = acc[fr][fc][rr] + bias;
        }
    }
}

extern "C" void kernel_launch(void* const* d_in, const int* in_sizes, int n_in,
                              void* d_out, int out_size, void* d_ws, size_t ws_size,
                              hipStream_t stream) {
    const float* data = (const float*)d_in[0];
    const float* Wq   = (const float*)d_in[1];
    const float* Wk   = (const float*)d_in[2];
    const float* Wv   = (const float*)d_in[3];
    const float* Wp   = (const float*)d_in[4];
    const float* bp   = (const float*)d_in[5];
    float* outp = (float*)d_out;

    const size_t S = (size_t)BI * HH * TT * DD;  // 8,388,608 elems per buffer
    u16* qws = (u16*)d_ws;
    u16* kws = qws + S;
    u16* vws = kws + S;
    u16* aws = vws + S;

    qkv_gemm<<<dim3(64, 16, 3), 256, 0, stream>>>(data, Wq, Wk, Wv, qws, kws, vws);
    attn<<<dim3(32, 64), 256, 0, stream>>>(qws, kws, vws, aws);
    proj_gemm<<<dim3(64, 16), 256, 0, stream>>>(aws, Wp, bp, outp);
}

// Round 4
// 544.563 us; speedup vs baseline: 1.2885x; 1.2885x over previous
//
#include <hip/hip_runtime.h>

#define BI 4
#define TT 2048
#define EE 1024
#define HH 16
#define DD 64
// M = BI*TT = 8192

typedef short bf16x8 __attribute__((ext_vector_type(8)));
typedef float f32x4 __attribute__((ext_vector_type(4)));
typedef unsigned short u16;

#define AS1 __attribute__((address_space(1)))
#define AS3 __attribute__((address_space(3)))
#define GLOADLDS16(g, l) __builtin_amdgcn_global_load_lds((const AS1 void*)(g), (AS3 void*)(l), 16, 0, 0)

__device__ __forceinline__ float bf2f(u16 v) {
    unsigned int u = ((unsigned int)v) << 16;
    return __builtin_bit_cast(float, u);
}
__device__ __forceinline__ u16 f2bf(float f) {
    unsigned int u = __builtin_bit_cast(unsigned int, f);
    unsigned int r = (u + 0x7fffu + ((u >> 16) & 1u)) >> 16;
    return (u16)r;
}

// ---------------- Kernel 1: QKV projection ----------------
// z=0: q[b][h][t][d]*0.125, z=1: k[b][h][t][d], z=2: vT[b][h][d][t] (operand-swapped MFMA)
__global__ __launch_bounds__(256) void qkv_gemm(
    const float* __restrict__ data, const float* __restrict__ Wq,
    const float* __restrict__ Wk, const float* __restrict__ Wv,
    u16* __restrict__ qws, u16* __restrict__ kws, u16* __restrict__ vws)
{
    const int z = blockIdx.z;
    const float* W = (z == 0) ? Wq : ((z == 1) ? Wk : Wv);
    u16* out = (z == 0) ? qws : ((z == 1) ? kws : vws);
    const int h  = blockIdx.y;
    const int m0 = blockIdx.x * 128;
    const int b  = m0 / TT;
    const int t0 = m0 % TT;

    __shared__ u16 As[128][72];   // A tile [t-row][e] (bf16)
    __shared__ u16 Bs[64][72];    // B^T tile [d][e] (bf16)

    const int tid = threadIdx.x;
    const int l  = tid & 63;
    const int w  = tid >> 6;
    const int wr = w >> 1;
    const int wc = w & 1;
    const int lr = l & 15;
    const int lk = l >> 4;

    f32x4 acc[4][2];
    for (int i = 0; i < 4; ++i)
        for (int j = 0; j < 2; ++j)
            acc[i][j] = (f32x4){0.f, 0.f, 0.f, 0.f};

    for (int e0 = 0; e0 < EE; e0 += 64) {
        const float* dsrc = data + (size_t)m0 * EE + e0;
        for (int it = 0; it < 8; ++it) {
            int v = tid + it * 256;
            int row = v >> 4, c4 = v & 15;
            float4 x = *reinterpret_cast<const float4*>(dsrc + (size_t)row * EE + c4 * 4);
            ushort4 p;
            p.x = f2bf(x.x); p.y = f2bf(x.y); p.z = f2bf(x.z); p.w = f2bf(x.w);
            *reinterpret_cast<ushort4*>(&As[row][c4 * 4]) = p;
        }
        const float* wsrc = W + ((size_t)h * EE + e0) * DD;
        for (int it = 0; it < 4; ++it) {
            int v = tid + it * 256;
            int e = v >> 4, d4 = v & 15;
            float4 x = *reinterpret_cast<const float4*>(wsrc + (size_t)e * DD + d4 * 4);
            Bs[d4 * 4 + 0][e] = f2bf(x.x);
            Bs[d4 * 4 + 1][e] = f2bf(x.y);
            Bs[d4 * 4 + 2][e] = f2bf(x.z);
            Bs[d4 * 4 + 3][e] = f2bf(x.w);
        }
        __syncthreads();
        for (int kk = 0; kk < 64; kk += 32) {
            bf16x8 a[4], bb[2];
            for (int fr = 0; fr < 4; ++fr)
                a[fr] = *reinterpret_cast<const bf16x8*>(&As[wr * 64 + fr * 16 + lr][kk + lk * 8]);
            for (int fc = 0; fc < 2; ++fc)
                bb[fc] = *reinterpret_cast<const bf16x8*>(&Bs[wc * 32 + fc * 16 + lr][kk + lk * 8]);
            if (z == 2) {
                for (int fr = 0; fr < 4; ++fr)
                    for (int fc = 0; fc < 2; ++fc)
                        acc[fr][fc] = __builtin_amdgcn_mfma_f32_16x16x32_bf16(bb[fc], a[fr], acc[fr][fc], 0, 0, 0);
            } else {
                for (int fr = 0; fr < 4; ++fr)
                    for (int fc = 0; fc < 2; ++fc)
                        acc[fr][fc] = __builtin_amdgcn_mfma_f32_16x16x32_bf16(a[fr], bb[fc], acc[fr][fc], 0, 0, 0);
            }
        }
        __syncthreads();
    }

    if (z == 2) {
        // acc[fr][fc] = C'[d][t]: row = d = wc*32+fc*16+lk*4+rr, col = t = wr*64+fr*16+lr
        for (int fr = 0; fr < 4; ++fr) {
            int tcol = wr * 64 + fr * 16 + lr;
            for (int fc = 0; fc < 2; ++fc) {
                int drow = wc * 32 + fc * 16 + lk * 4;
                size_t base = (((size_t)(b * HH + h)) * DD + drow) * TT + (t0 + tcol);
                for (int rr = 0; rr < 4; ++rr)
                    out[base + (size_t)rr * TT] = f2bf(acc[fr][fc][rr]);
            }
        }
    } else {
        const float scale = (z == 0) ? 0.125f : 1.0f;
        for (int fr = 0; fr < 4; ++fr) {
            int row = wr * 64 + fr * 16 + lk * 4;
            for (int fc = 0; fc < 2; ++fc) {
                int col = wc * 32 + fc * 16 + lr;
                size_t base = (((size_t)b * HH + h) * TT + (size_t)(t0 + row)) * DD + col;
                for (int rr = 0; rr < 4; ++rr)
                    out[base + (size_t)rr * DD] = f2bf(acc[fr][fc][rr] * scale);
            }
        }
    }
}

// ---------------- Kernel 2: causal flash attention v2 ----------------
// KVBLK=64, double-buffered global_load_lds staging, XOR-swizzled LDS reads.
__global__ __launch_bounds__(256) void attn(
    const u16* __restrict__ qws, const u16* __restrict__ kws,
    const u16* __restrict__ vtws, u16* __restrict__ aout)
{
    const int qt = 31 - blockIdx.x;   // reversed: heaviest blocks first
    const int bh = blockIdx.y;
    const int b = bh >> 4, h = bh & 15;
    const int q0 = qt * 64;

    __shared__ u16 Ks[2][64 * 64];    // K tile [s][d], 128B rows, swizzled content
    __shared__ u16 Vs[2][64 * 64];    // vT tile [d][s], 128B rows, swizzled content
    __shared__ u16 Pb[4][16 * 68];    // per-wave P round-trip, stride 68 (2-way free)

    const int tid = threadIdx.x;
    const int l = tid & 63;
    const int w = tid >> 6;
    const int lr = l & 15, lk = l >> 4;
    const int lrow = l >> 3, lslot = l & 7;

    const size_t kvbase = (size_t)bh * TT * DD;
    const int qb = q0 + w * 16;

    // q fragments (registers), then drain vmcnt so counted waits are sound
    bf16x8 qf[2];
    for (int kk = 0; kk < 2; ++kk)
        qf[kk] = *reinterpret_cast<const bf16x8*>(qws + kvbase + (size_t)(qb + lr) * DD + kk * 32 + lk * 8);
    asm volatile("s_waitcnt vmcnt(0)" ::: "memory");

    // stage tile jt into buffer bufi: 4 global_load_lds per wave (2 K + 2 vT)
    auto stage = [&](int jt, int bufi) {
        const int s0 = jt * 64;
        for (int ii = 0; ii < 2; ++ii) {
            const int row = w * 16 + ii * 8 + lrow;       // 0..63
            const int sw = lslot ^ (row & 7);             // inverse-swizzled source slot
            const u16* gk = kws + kvbase + (size_t)(s0 + row) * DD + sw * 8;
            GLOADLDS16(gk, &Ks[bufi][(w * 16 + ii * 8) * 64]);
            const u16* gv = vtws + kvbase + (size_t)row * TT + s0 + sw * 8;
            GLOADLDS16(gv, &Vs[bufi][(w * 16 + ii * 8) * 64]);
        }
    };

    f32x4 oacc[4];
    for (int i = 0; i < 4; ++i) oacc[i] = (f32x4){0.f, 0.f, 0.f, 0.f};
    float mrow[4], lsum[4];
    for (int r = 0; r < 4; ++r) { mrow[r] = -INFINITY; lsum[r] = 0.f; }

    const int ntiles = qt + 1;
    stage(0, 0);

    for (int j = 0; j < ntiles; ++j) {
        const int cur = j & 1;
        if (j + 1 < ntiles) {
            stage(j + 1, cur ^ 1);
            asm volatile("s_waitcnt vmcnt(4)" ::: "memory");
        } else {
            asm volatile("s_waitcnt vmcnt(0)" ::: "memory");
        }
        __builtin_amdgcn_sched_barrier(0);
        __builtin_amdgcn_s_barrier();
        __builtin_amdgcn_sched_barrier(0);

        const u16* Kb = &Ks[cur][0];
        const u16* Vb = &Vs[cur][0];

        // QK^T: sc[fc] covers s-cols fc*16..fc*16+15
        f32x4 sc[4];
        for (int fc = 0; fc < 4; ++fc) {
            sc[fc] = (f32x4){0.f, 0.f, 0.f, 0.f};
            const int row = fc * 16 + lr;
            const int sw = (row & 7) << 3;
            for (int kk = 0; kk < 2; ++kk) {
                bf16x8 kf = *reinterpret_cast<const bf16x8*>(Kb + row * 64 + ((kk * 32 + lk * 8) ^ sw));
                sc[fc] = __builtin_amdgcn_mfma_f32_16x16x32_bf16(qf[kk], kf, sc[fc], 0, 0, 0);
            }
        }
        // causal mask: only the diagonal tile needs it
        if (j == ntiles - 1) {
            for (int fc = 0; fc < 4; ++fc)
                for (int r = 0; r < 4; ++r)
                    if (fc * 16 + lr > w * 16 + lk * 4 + r) sc[fc][r] = -INFINITY;
        }
        // online softmax over 64 s (16-lane row groups)
        float mx[4];
        for (int r = 0; r < 4; ++r)
            mx[r] = fmaxf(fmaxf(sc[0][r], sc[1][r]), fmaxf(sc[2][r], sc[3][r]));
        for (int off = 1; off < 16; off <<= 1)
            for (int r = 0; r < 4; ++r) mx[r] = fmaxf(mx[r], __shfl_xor(mx[r], off, 64));
        float mnew[4], alpha[4];
        for (int r = 0; r < 4; ++r) {
            mnew[r] = fmaxf(mrow[r], mx[r]);
            alpha[r] = exp2f((mrow[r] - mnew[r]) * 1.44269504f);
        }
        float p[4][4], rsum[4];
        for (int r = 0; r < 4; ++r) rsum[r] = 0.f;
        for (int fc = 0; fc < 4; ++fc)
            for (int r = 0; r < 4; ++r) {
                p[fc][r] = exp2f((sc[fc][r] - mnew[r]) * 1.44269504f);
                rsum[r] += p[fc][r];
            }
        for (int off = 1; off < 16; off <<= 1)
            for (int r = 0; r < 4; ++r) rsum[r] += __shfl_xor(rsum[r], off, 64);
        for (int r = 0; r < 4; ++r) {
            lsum[r] = lsum[r] * alpha[r] + rsum[r];
            mrow[r] = mnew[r];
        }
        for (int fc = 0; fc < 4; ++fc)
            for (int r = 0; r < 4; ++r)
                oacc[fc][r] *= alpha[r];
        // P -> LDS (stride 68: conflict-free) -> A-fragment
        for (int fc = 0; fc < 4; ++fc)
            for (int r = 0; r < 4; ++r)
                Pb[w][(lk * 4 + r) * 68 + fc * 16 + lr] = f2bf(p[fc][r]);
        bf16x8 pa[2];
        for (int ks = 0; ks < 2; ++ks)
            pa[ks] = *reinterpret_cast<const bf16x8*>(&Pb[w][lr * 68 + ks * 32 + lk * 8]);
        // PV: oacc[fc] covers d-cols fc*16..fc*16+15
        for (int fc = 0; fc < 4; ++fc) {
            const int row = fc * 16 + lr;
            const int sw = (row & 7) << 3;
            for (int ks = 0; ks < 2; ++ks) {
                bf16x8 vf = *reinterpret_cast<const bf16x8*>(Vb + row * 64 + ((ks * 32 + lk * 8) ^ sw));
                oacc[fc] = __builtin_amdgcn_mfma_f32_16x16x32_bf16(pa[ks], vf, oacc[fc], 0, 0, 0);
            }
        }
        __builtin_amdgcn_sched_barrier(0);
        __builtin_amdgcn_s_barrier();
        __builtin_amdgcn_sched_barrier(0);
    }

    // epilogue: concat-head layout [b][t][h*64+d]
    for (int fc = 0; fc < 4; ++fc) {
        int dcol = fc * 16 + lr;
        for (int r = 0; r < 4; ++r) {
            int qrow = qb + lk * 4 + r;
            float v = oacc[fc][r] / lsum[r];
            aout[((size_t)b * TT + qrow) * EE + (size_t)h * DD + dcol] = f2bf(v);
        }
    }
}

// ---------------- Kernel 3: output projection + bias ----------------
// A: bf16 workspace [M,E]; Wp: f32 [E,E]; bp: f32 [E]; out: f32 [M,E]
__global__ __launch_bounds__(256) void proj_gemm(
    const u16* __restrict__ A, const float* __restrict__ Wp,
    const float* __restrict__ bp, float* __restrict__ out)
{
    const int m0 = blockIdx.x * 128;
    const int n0 = blockIdx.y * 64;

    __shared__ u16 As[128][72];
    __shared__ u16 Bs[64][72];

    const int tid = threadIdx.x;
    const int l  = tid & 63;
    const int w  = tid >> 6;
    const int wr = w >> 1;
    const int wc = w & 1;
    const int lr = l & 15;
    const int lk = l >> 4;

    f32x4 acc[4][2];
    for (int i = 0; i < 4; ++i)
        for (int j = 0; j < 2; ++j)
            acc[i][j] = (f32x4){0.f, 0.f, 0.f, 0.f};

    for (int e0 = 0; e0 < EE; e0 += 64) {
        const uint4* asrc = reinterpret_cast<const uint4*>(A);
        for (int it = 0; it < 4; ++it) {
            int v = tid + it * 256;
            int row = v >> 3, c8 = v & 7;
            uint4 x = asrc[(((size_t)(m0 + row)) * EE + e0) / 8 + c8];
            *reinterpret_cast<uint4*>(&As[row][c8 * 8]) = x;
        }
        const float* wsrc = Wp + (size_t)e0 * EE + n0;
        for (int it = 0; it < 4; ++it) {
            int v = tid + it * 256;
            int e = v >> 4, n4 = v & 15;
            float4 x = *reinterpret_cast<const float4*>(wsrc + (size_t)e * EE + n4 * 4);
            Bs[n4 * 4 + 0][e] = f2bf(x.x);
            Bs[n4 * 4 + 1][e] = f2bf(x.y);
            Bs[n4 * 4 + 2][e] = f2bf(x.z);
            Bs[n4 * 4 + 3][e] = f2bf(x.w);
        }
        __syncthreads();
        for (int kk = 0; kk < 64; kk += 32) {
            bf16x8 a[4], bb[2];
            for (int fr = 0; fr < 4; ++fr)
                a[fr] = *reinterpret_cast<const bf16x8*>(&As[wr * 64 + fr * 16 + lr][kk + lk * 8]);
            for (int fc = 0; fc < 2; ++fc)
                bb[fc] = *reinterpret_cast<const bf16x8*>(&Bs[wc * 32 + fc * 16 + lr][kk + lk * 8]);
            for (int fr = 0; fr < 4; ++fr)
                for (int fc = 0; fc < 2; ++fc)
                    acc[fr][fc] = __builtin_amdgcn_mfma_f32_16x16x32_bf16(a[fr], bb[fc], acc[fr][fc], 0, 0, 0);
        }
        __syncthreads();
    }

    for (int fr = 0; fr < 4; ++fr) {
        int row = wr * 64 + fr * 16 + lk * 4;
        for (int fc = 0; fc < 2; ++fc) {
            int col = n0 + wc * 32 + fc * 16 + lr;
            float bias = bp[col];
            for (int rr = 0; rr < 4; ++rr)
                out[((size_t)(m0 + row + rr)) * EE + col] = acc[fr][fc][rr] + bias;
        }
    }
}

extern "C" void kernel_launch(void* const* d_in, const int* in_sizes, int n_in,
                              void* d_out, int out_size, void* d_ws, size_t ws_size,
                              hipStream_t stream) {
    const float* data = (const float*)d_in[0];
    const float* Wq   = (const float*)d_in[1];
    const float* Wk   = (const float*)d_in[2];
    const float* Wv   = (const float*)d_in[3];
    const float* Wp   = (const float*)d_in[4];
    const float* bp   = (const float*)d_in[5];
    float* outp = (float*)d_out;

    const size_t S = (size_t)BI * HH * TT * DD;  // 8,388,608 elems per buffer
    u16* qws = (u16*)d_ws;
    u16* kws = qws + S;
    u16* vtws = kws + S;   // [B][H][D][T]
    u16* aws  = vtws + S;

    qkv_gemm<<<dim3(64, 16, 3), 256, 0, stream>>>(data, Wq, Wk, Wv, qws, kws, vtws);
    attn<<<dim3(32, 64), 256, 0, stream>>>(qws, kws, vtws, aws);
    proj_gemm<<<dim3(64, 16), 256, 0, stream>>>(aws, Wp, bp, outp);
}